// Round 21
// baseline (1110.773 us; speedup 1.0000x reference)
//
#include <hip/hip_runtime.h>
#include <hip/hip_bf16.h>

// Decoder_21208548508049 — round 21: scalar-path x for phase A.
// The 67%-VALU cap (r14/r20, twice-measured) is LDS-issue oversubscription:
// 8 ds_read_b128 (96 CU-shared cy) per 256 per-SIMD VALU cy at 16 waves/CU
// = 1.5x. But x-reads are WAVE-UNIFORM -> route them through the scalar path
// (s_load via K$) instead of LDS: zero LDS instrs, zero barriers; only the
// W stream (L1 ratio 1.0) remains on the vector side.
//   Phase A (lif_phaseA_s): 512 thr (8 waves = 4 tok-slots x 2 e-halves),
//   tok made uniform via readfirstlane -> x loads scalarize. Per-(t,e) fmaf
//   chain VERBATIM r14 (bias-init, d-ascending, t-chunks of 8) -> spikes
//   bit-identical. Phase B: r14's lif_phaseB4 (~80us).
// Fallback tiers unchanged.
//
// T=32,B=8,N=256,D=512.

#define TT 32
#define CH 8
#define BB 8
#define NN 256
#define DD 512

typedef __attribute__((ext_vector_type(8))) short short8;
typedef __attribute__((ext_vector_type(4))) float f32x4;

__device__ __forceinline__ unsigned short f2bf(float f) {
    __hip_bfloat16 h = __float2bfloat16(f);
    return *reinterpret_cast<unsigned short*>(&h);
}

// ---- pre-kernel: Wt[p][d] = bf16(Wr[d][p]) ----
__global__ void cast_transpose_wr(const float* __restrict__ Wr,
                                  unsigned short* __restrict__ Wt) {
    int idx = blockIdx.x * 256 + threadIdx.x;      // 0..262143
    int d = idx >> 9;
    int p = idx & 511;
    Wt[p * DD + d] = f2bf(Wr[idx]);
}

// ========== Tier-1 Phase A: GEMM1 (exact f32, scalar-x) + LIF -> g =========
// 512 blocks x 512 thr; wave = (token slot, e-half); NO LDS, NO barriers.
__global__ __launch_bounds__(512, 2) void lif_phaseA_s(
    const float* __restrict__ x,      // [T,B,N,D]
    const float* __restrict__ tr_mx,  // [B,N,D]
    const float* __restrict__ Wl,     // [D,D]
    const float* __restrict__ bl,     // [D]
    unsigned short* __restrict__ gws) // [B*N*T, D] bf16: g[tok*32+t][e]
{
    const int tid  = threadIdx.x;         // 0..511
    const int lane = tid & 63;
    // wave id, forced wave-uniform into an SGPR so x addresses scalarize
    const int wv = __builtin_amdgcn_readfirstlane(tid >> 6);   // 0..7
    const int tq = wv >> 1;               // token slot 0..3 (uniform)
    const int eh = wv & 1;                // e-half 0/1 (uniform)
    const int e0 = eh * 256 + lane * 4;   // owned e-columns
    const int tok = blockIdx.x * 4 + tq;  // uniform per wave
    const size_t base = (size_t)tok * DD;
    const size_t st   = (size_t)BB * NN * DD;
    const float* __restrict__ xw = x + base;   // uniform base pointer

    float acc[CH][4];
    float m[4];
    {
        const float4 m4 = *reinterpret_cast<const float4*>(&tr_mx[base + e0]);
        m[0] = m4.x; m[1] = m4.y; m[2] = m4.z; m[3] = m4.w;
    }
    const float4 blv = *reinterpret_cast<const float4*>(&bl[e0]);
    const float blr[4] = {blv.x, blv.y, blv.z, blv.w};

    #pragma unroll 1
    for (int tg = 0; tg < 4; ++tg) {
        #pragma unroll
        for (int i = 0; i < CH; ++i)
            #pragma unroll
            for (int e = 0; e < 4; ++e) acc[i][e] = blr[e];

        #pragma unroll 2
        for (int d = 0; d < DD; d += 4) {
            // per-thread W loads (coalesced 1KB per wave-half)
            const float4 w0 = *reinterpret_cast<const float4*>(&Wl[(size_t)(d + 0) * DD + e0]);
            const float4 w1 = *reinterpret_cast<const float4*>(&Wl[(size_t)(d + 1) * DD + e0]);
            const float4 w2 = *reinterpret_cast<const float4*>(&Wl[(size_t)(d + 2) * DD + e0]);
            const float4 w3 = *reinterpret_cast<const float4*>(&Wl[(size_t)(d + 3) * DD + e0]);
            #pragma unroll
            for (int i = 0; i < CH; ++i) {
                // WAVE-UNIFORM x load (tok, t, d all uniform) -> s_load path
                const float4 xv = *reinterpret_cast<const float4*>(
                    &xw[(size_t)(tg * CH + i) * st + d]);
                // d-ascending fmaf chain per (t,e): identical to r14/r20 pass
                acc[i][0] = fmaf(xv.x, w0.x, acc[i][0]);
                acc[i][1] = fmaf(xv.x, w0.y, acc[i][1]);
                acc[i][2] = fmaf(xv.x, w0.z, acc[i][2]);
                acc[i][3] = fmaf(xv.x, w0.w, acc[i][3]);
                acc[i][0] = fmaf(xv.y, w1.x, acc[i][0]);
                acc[i][1] = fmaf(xv.y, w1.y, acc[i][1]);
                acc[i][2] = fmaf(xv.y, w1.z, acc[i][2]);
                acc[i][3] = fmaf(xv.y, w1.w, acc[i][3]);
                acc[i][0] = fmaf(xv.z, w2.x, acc[i][0]);
                acc[i][1] = fmaf(xv.z, w2.y, acc[i][1]);
                acc[i][2] = fmaf(xv.z, w2.z, acc[i][2]);
                acc[i][3] = fmaf(xv.z, w2.w, acc[i][3]);
                acc[i][0] = fmaf(xv.w, w3.x, acc[i][0]);
                acc[i][1] = fmaf(xv.w, w3.y, acc[i][1]);
                acc[i][2] = fmaf(xv.w, w3.z, acc[i][2]);
                acc[i][3] = fmaf(xv.w, w3.w, acc[i][3]);
            }
        }

        // LIF (identical per-(t,e) arithmetic); per-thread x re-read (L2-hot);
        // g = s?0:x -> bf16 workspace (contiguous 512B per wave)
        #pragma unroll
        for (int i = 0; i < CH; ++i) {
            const int t = tg * CH + i;
            const float4 xv = *reinterpret_cast<const float4*>(&x[(size_t)t * st + base + e0]);
            const float xr[4] = {xv.x, xv.y, xv.z, xv.w};
            float g[4];
            #pragma unroll
            for (int e = 0; e < 4; ++e) {
                m[e] = m[e] + (acc[i][e] - m[e]) * 0.5f;
                const float s = (m[e] - 1.0f > 0.0f) ? 1.0f : 0.0f;
                g[e] = (s > 0.0f) ? 0.0f : xr[e];
                m[e] *= (1.0f - s);
            }
            uint2 p;
            p.x = (unsigned)f2bf(g[0]) | ((unsigned)f2bf(g[1]) << 16);
            p.y = (unsigned)f2bf(g[2]) | ((unsigned)f2bf(g[3]) << 16);
            *reinterpret_cast<uint2*>(&gws[((size_t)tok * TT + t) * DD + e0]) = p;
        }
    }
}

// ========== Tier-1 Phase B: pure bf16 GEMM, 2 tokens per wave (r14) ========
__global__ __launch_bounds__(512, 2) void lif_phaseB4(
    const unsigned short* __restrict__ gws,  // [B*N*T, D] bf16
    const unsigned short* __restrict__ Wt,   // [D,D] bf16 transposed
    const float* __restrict__ br,            // [D]
    float* __restrict__ out)                 // [T,B,N,D]
{
    const int tid = threadIdx.x;          // 0..511
    const int w    = tid >> 6;            // 0..7
    const int lane = tid & 63;
    const int hB   = w & 1;               // t-half
    const int q    = w >> 1;              // col quarter (128 cols)
    const int lcol = lane & 15;
    const int lkg  = lane >> 4;           // 0..3
    const int tA   = hB * 16 + lcol;      // A row (t) this lane supplies
    const size_t st = (size_t)BB * NN * DD;
    const int colb = q * 128;
    const int tok0 = blockIdx.x * 2;

    const unsigned short* arow0 = &gws[((size_t)tok0 * TT + tA) * DD];
    const unsigned short* arow1 = &gws[((size_t)(tok0 + 1) * TT + tA) * DD];

    f32x4 acc0[8], acc1[8];
    #pragma unroll
    for (int nt = 0; nt < 8; ++nt) {
        const float b = br[colb + nt * 16 + lcol];
        acc0[nt] = (f32x4){b, b, b, b};
        acc1[nt] = (f32x4){b, b, b, b};
    }

    #pragma unroll 1
    for (int ks = 0; ks < 16; ++ks) {
        const int kb = ks * 32 + lkg * 8;
        const short8 a0 = *reinterpret_cast<const short8*>(&arow0[kb]);
        const short8 a1 = *reinterpret_cast<const short8*>(&arow1[kb]);
        #pragma unroll
        for (int nt = 0; nt < 8; ++nt) {
            const int col = colb + nt * 16 + lcol;
            const short8 bf = *reinterpret_cast<const short8*>(&Wt[(size_t)col * DD + kb]);
            acc0[nt] = __builtin_amdgcn_mfma_f32_16x16x32_bf16(a0, bf, acc0[nt], 0, 0, 0);
            acc1[nt] = __builtin_amdgcn_mfma_f32_16x16x32_bf16(a1, bf, acc1[nt], 0, 0, 0);
        }
    }

    // epilogue: C/D layout col=lane&15, row=(lane>>4)*4+r (verified r7/r10/r13)
    #pragma unroll
    for (int nt = 0; nt < 8; ++nt) {
        const int col = colb + nt * 16 + lcol;
        #pragma unroll
        for (int r = 0; r < 4; ++r) {
            const int t = hB * 16 + lkg * 4 + r;
            out[(size_t)t * st + (size_t)tok0 * DD + col]       = acc0[nt][r];
            out[(size_t)t * st + (size_t)(tok0 + 1) * DD + col] = acc1[nt][r];
        }
    }
}

// ========== Tier-2 Phase A: GEMM1+LIF -> global bitmask (r11) ==============
__global__ __launch_bounds__(128, 4) void lif_phaseA_m(
    const float* __restrict__ x, const float* __restrict__ tr_mx,
    const float* __restrict__ Wl, const float* __restrict__ bl,
    unsigned* __restrict__ gmsk)
{
    __shared__ __align__(16) float xs[CH * 256];

    const int tid = threadIdx.x;
    const int tok = blockIdx.x;
    const int e0  = tid * 4;
    const size_t base = (size_t)tok * DD;
    const size_t st   = (size_t)BB * NN * DD;

    float acc[CH][4];
    float4 m4 = *reinterpret_cast<const float4*>(&tr_mx[base + e0]);
    float m[4] = {m4.x, m4.y, m4.z, m4.w};
    unsigned mc[4] = {0u, 0u, 0u, 0u};
    const float4 blv = *reinterpret_cast<const float4*>(&bl[e0]);
    const float blr[4] = {blv.x, blv.y, blv.z, blv.w};

    #pragma unroll 1
    for (int tg = 0; tg < 4; ++tg) {
        #pragma unroll
        for (int i = 0; i < CH; ++i)
            #pragma unroll
            for (int e = 0; e < 4; ++e) acc[i][e] = blr[e];

        #pragma unroll 1
        for (int h = 0; h < 2; ++h) {
            #pragma unroll
            for (int r = 0; r < 4; ++r) {
                const int flat = r * 128 + tid;
                const int row  = flat >> 6;
                const int c4   = flat & 63;
                const float4 v = *reinterpret_cast<const float4*>(
                    &x[(size_t)(tg * CH + row) * st + base + h * 256 + c4 * 4]);
                *reinterpret_cast<float4*>(&xs[row * 256 + c4 * 4]) = v;
            }
            __syncthreads();

            #pragma unroll 2
            for (int dd_ = 0; dd_ < 256; dd_ += 4) {
                const int d = h * 256 + dd_;
                const float4 w0 = *reinterpret_cast<const float4*>(&Wl[(size_t)(d + 0) * DD + e0]);
                const float4 w1 = *reinterpret_cast<const float4*>(&Wl[(size_t)(d + 1) * DD + e0]);
                const float4 w2 = *reinterpret_cast<const float4*>(&Wl[(size_t)(d + 2) * DD + e0]);
                const float4 w3 = *reinterpret_cast<const float4*>(&Wl[(size_t)(d + 3) * DD + e0]);
                #pragma unroll
                for (int i = 0; i < CH; ++i) {
                    const float4 xv = *reinterpret_cast<const float4*>(&xs[i * 256 + dd_]);
                    acc[i][0] = fmaf(xv.x, w0.x, acc[i][0]);
                    acc[i][1] = fmaf(xv.x, w0.y, acc[i][1]);
                    acc[i][2] = fmaf(xv.x, w0.z, acc[i][2]);
                    acc[i][3] = fmaf(xv.x, w0.w, acc[i][3]);
                    acc[i][0] = fmaf(xv.y, w1.x, acc[i][0]);
                    acc[i][1] = fmaf(xv.y, w1.y, acc[i][1]);
                    acc[i][2] = fmaf(xv.y, w1.z, acc[i][2]);
                    acc[i][3] = fmaf(xv.y, w1.w, acc[i][3]);
                    acc[i][0] = fmaf(xv.z, w2.x, acc[i][0]);
                    acc[i][1] = fmaf(xv.z, w2.y, acc[i][1]);
                    acc[i][2] = fmaf(xv.z, w2.z, acc[i][2]);
                    acc[i][3] = fmaf(xv.z, w2.w, acc[i][3]);
                    acc[i][0] = fmaf(xv.w, w3.x, acc[i][0]);
                    acc[i][1] = fmaf(xv.w, w3.y, acc[i][1]);
                    acc[i][2] = fmaf(xv.w, w3.z, acc[i][2]);
                    acc[i][3] = fmaf(xv.w, w3.w, acc[i][3]);
                }
            }
            __syncthreads();
        }

        #pragma unroll
        for (int i = 0; i < CH; ++i) {
            const int t = tg * CH + i;
            #pragma unroll
            for (int e = 0; e < 4; ++e) {
                m[e] = m[e] + (acc[i][e] - m[e]) * 0.5f;
                const float s = (m[e] - 1.0f > 0.0f) ? 1.0f : 0.0f;
                mc[e] |= (s > 0.0f) ? (1u << t) : 0u;
                m[e] *= (1.0f - s);
            }
        }
    }

    uint4 mv;
    mv.x = mc[0]; mv.y = mc[1]; mv.z = mc[2]; mv.w = mc[3];
    *reinterpret_cast<uint4*>(&gmsk[base + e0]) = mv;
}

// ========== Tier-2 Phase B: r12's MFMA GEMM2 (mask + x) ====================
template<bool UW>
__global__ __launch_bounds__(256, 2) void lif_phaseB2(
    const float* __restrict__ x, const float* __restrict__ Wr,
    const float* __restrict__ br, const unsigned short* __restrict__ Wt,
    const unsigned* __restrict__ gmsk, float* __restrict__ out)
{
    __shared__ __align__(16) unsigned ms[2 * DD];

    const int tid = threadIdx.x;
    const size_t st = (size_t)BB * NN * DD;
    {
        const uint4 v = *reinterpret_cast<const uint4*>(
            &gmsk[(size_t)blockIdx.x * 2 * DD + tid * 4]);
        *reinterpret_cast<uint4*>(&ms[tid * 4]) = v;
    }
    __syncthreads();

    const int wv   = tid >> 6;
    const int lane = tid & 63;
    const int qB   = wv >> 1;
    const int hB   = wv & 1;
    const int lcol = lane & 15;
    const int lkg  = lane >> 4;
    const int tA   = hB * 16 + lcol;
    const size_t baseB = (size_t)(blockIdx.x * 2 + qB) * DD;
    const unsigned* mq = &ms[qB * DD];
    const float* xrow = &x[(size_t)tA * st + baseB];

    #pragma unroll 1
    for (int pass = 0; pass < 4; ++pass) {
        const int colb = pass * 128;
        f32x4 acc[8];
        #pragma unroll
        for (int nt = 0; nt < 8; ++nt) {
            const float b = br[colb + nt * 16 + lcol];
            acc[nt] = (f32x4){b, b, b, b};
        }
        #pragma unroll 1
        for (int ks = 0; ks < 16; ++ks) {
            const int kb = ks * 32 + lkg * 8;
            const float4 x0 = *reinterpret_cast<const float4*>(&xrow[kb]);
            const float4 x1 = *reinterpret_cast<const float4*>(&xrow[kb + 4]);
            const uint4 m0 = *reinterpret_cast<const uint4*>(&mq[kb]);
            const uint4 m1 = *reinterpret_cast<const uint4*>(&mq[kb + 4]);
            short8 a;
            a[0] = (short)f2bf(((m0.x >> tA) & 1u) ? 0.0f : x0.x);
            a[1] = (short)f2bf(((m0.y >> tA) & 1u) ? 0.0f : x0.y);
            a[2] = (short)f2bf(((m0.z >> tA) & 1u) ? 0.0f : x0.z);
            a[3] = (short)f2bf(((m0.w >> tA) & 1u) ? 0.0f : x0.w);
            a[4] = (short)f2bf(((m1.x >> tA) & 1u) ? 0.0f : x1.x);
            a[5] = (short)f2bf(((m1.y >> tA) & 1u) ? 0.0f : x1.y);
            a[6] = (short)f2bf(((m1.z >> tA) & 1u) ? 0.0f : x1.z);
            a[7] = (short)f2bf(((m1.w >> tA) & 1u) ? 0.0f : x1.w);
            #pragma unroll
            for (int nt = 0; nt < 8; ++nt) {
                const int col = colb + nt * 16 + lcol;
                short8 bf;
                if (UW) {
                    bf = *reinterpret_cast<const short8*>(&Wt[(size_t)col * DD + kb]);
                } else {
                    #pragma unroll
                    for (int j = 0; j < 8; ++j)
                        bf[j] = (short)f2bf(Wr[(size_t)(kb + j) * DD + col]);
                }
                acc[nt] = __builtin_amdgcn_mfma_f32_16x16x32_bf16(a, bf, acc[nt], 0, 0, 0);
            }
        }
        #pragma unroll
        for (int nt = 0; nt < 8; ++nt) {
            const int col = colb + nt * 16 + lcol;
            #pragma unroll
            for (int r = 0; r < 4; ++r) {
                const int t = hB * 16 + lkg * 4 + r;
                out[(size_t)t * st + baseB + col] = acc[nt][r];
            }
        }
    }
}

extern "C" void kernel_launch(void* const* d_in, const int* in_sizes, int n_in,
                              void* d_out, int out_size, void* d_ws, size_t ws_size,
                              hipStream_t stream) {
    const float* x     = (const float*)d_in[0];
    const float* tr_mx = (const float*)d_in[1];
    const float* Wl    = (const float*)d_in[2];
    const float* bl    = (const float*)d_in[3];
    const float* Wr    = (const float*)d_in[4];
    const float* br    = (const float*)d_in[5];
    float* out = (float*)d_out;

    const size_t g_bytes   = (size_t)BB * NN * TT * DD * 2;   // 67.1 MB
    const size_t wt_bytes  = (size_t)DD * DD * 2;             // 512 KB
    const size_t msk_bytes = (size_t)BB * NN * DD * 4;        // 4 MB

    if (ws_size >= g_bytes + wt_bytes) {
        unsigned short* gws = (unsigned short*)d_ws;
        unsigned short* Wt  = (unsigned short*)((char*)d_ws + g_bytes);
        cast_transpose_wr<<<dim3(1024), dim3(256), 0, stream>>>(Wr, Wt);
        lif_phaseA_s<<<dim3(BB * NN / 4), dim3(512), 0, stream>>>(x, tr_mx, Wl, bl, gws);
        lif_phaseB4<<<dim3(BB * NN / 2), dim3(512), 0, stream>>>(gws, Wt, br, out);
    } else if (ws_size >= msk_bytes + wt_bytes) {
        unsigned* gmsk = (unsigned*)d_ws;
        unsigned short* Wt = (unsigned short*)((char*)d_ws + msk_bytes);
        cast_transpose_wr<<<dim3(1024), dim3(256), 0, stream>>>(Wr, Wt);
        lif_phaseA_m<<<dim3(BB * NN), dim3(128), 0, stream>>>(x, tr_mx, Wl, bl, gmsk);
        lif_phaseB2<true><<<dim3(BB * NN / 2), dim3(256), 0, stream>>>(x, Wr, br, Wt, gmsk, out);
    } else if (ws_size >= msk_bytes) {
        unsigned* gmsk = (unsigned*)d_ws;
        lif_phaseA_m<<<dim3(BB * NN), dim3(128), 0, stream>>>(x, tr_mx, Wl, bl, gmsk);
        lif_phaseB2<false><<<dim3(BB * NN / 2), dim3(256), 0, stream>>>(x, Wr, br, nullptr, gmsk, out);
    }
}

// Round 22
// 623.226 us; speedup vs baseline: 1.7823x; 1.7823x over previous
//
#include <hip/hip_runtime.h>
#include <hip/hip_bf16.h>

// Decoder_21208548508049 — FINAL: round-14/20 champion (626us, absmax 0.03125).
// r21's scalar-x experiment refuted (1040us: "uniform" x loads compile to
// per-lane global broadcasts, no scalarization). Champion decomposition:
//   cast (~5us): Wt[p][d] = bf16(Wr[d][p])
//   lif_phaseA_g4 (~538us): GEMM1 exact-f32 fmaf chain + LIF -> g bf16.
//     4 tok/block, t=8/e=4 (plateau winner over 8 structural variants).
//     VALU 66% cap = joint LDS-broadcast + L1-W issue pressure; f32-only
//     (no fp32 MFMA on CDNA4; bf16 GEMM1 flips spikes -> absmax ~0.5 fail).
//   lif_phaseB4 (~80us): pure bf16-MFMA GEMM, 2 tokens/wave (~L2 floor).
//
// T=32,B=8,N=256,D=512.

#define TT 32
#define CH 8
#define BB 8
#define NN 256
#define DD 512

typedef __attribute__((ext_vector_type(8))) short short8;
typedef __attribute__((ext_vector_type(4))) float f32x4;

__device__ __forceinline__ unsigned short f2bf(float f) {
    __hip_bfloat16 h = __float2bfloat16(f);
    return *reinterpret_cast<unsigned short*>(&h);
}

// ---- pre-kernel: Wt[p][d] = bf16(Wr[d][p]) ----
__global__ void cast_transpose_wr(const float* __restrict__ Wr,
                                  unsigned short* __restrict__ Wt) {
    int idx = blockIdx.x * 256 + threadIdx.x;      // 0..262143
    int d = idx >> 9;
    int p = idx & 511;
    Wt[p * DD + d] = f2bf(Wr[idx]);
}

// ========== Tier-1 Phase A: GEMM1 (exact f32) + LIF -> g (bf16), 4 tok/blk ==
__global__ __launch_bounds__(512, 4) void lif_phaseA_g4(
    const float* __restrict__ x,      // [T,B,N,D]
    const float* __restrict__ tr_mx,  // [B,N,D]
    const float* __restrict__ Wl,     // [D,D]
    const float* __restrict__ bl,     // [D]
    unsigned short* __restrict__ gws) // [B*N*T, D] bf16: g[tok*32+t][e]
{
    __shared__ __align__(16) float xs[4 * CH * DD];   // 64 KB: 4 tokens x chunk

    const int tid = threadIdx.x;          // 0..511
    const int tq  = tid >> 7;             // token slot 0..3
    const int tl  = tid & 127;
    const int e0  = tl * 4;
    const int tok = blockIdx.x * 4 + tq;
    const size_t base = (size_t)tok * DD;
    const size_t st   = (size_t)BB * NN * DD;

    float acc[CH][4];
    float4 m4 = *reinterpret_cast<const float4*>(&tr_mx[base + e0]);
    float m[4] = {m4.x, m4.y, m4.z, m4.w};

    const float4 blv = *reinterpret_cast<const float4*>(&bl[e0]);
    const float blr[4] = {blv.x, blv.y, blv.z, blv.w};

    #pragma unroll 1
    for (int tg = 0; tg < 4; ++tg) {
        // stage x[tg*8..+7][4 tokens][0..511]: 8 float4/thread, coalesced
        #pragma unroll
        for (int r = 0; r < 8; ++r) {
            const int flat = r * 512 + tid;        // 0..4095
            const int q    = flat >> 10;           // token 0..3
            const int rem  = flat & 1023;
            const int row  = rem >> 7;             // 0..7
            const int c4   = rem & 127;
            const float4 v = *reinterpret_cast<const float4*>(
                &x[(size_t)(tg * CH + row) * st
                   + (size_t)(blockIdx.x * 4 + q) * DD + c4 * 4]);
            *reinterpret_cast<float4*>(&xs[(q * CH + row) * DD + c4 * 4]) = v;
        }
        __syncthreads();

        #pragma unroll
        for (int i = 0; i < CH; ++i)
            #pragma unroll
            for (int e = 0; e < 4; ++e) acc[i][e] = blr[e];

        const float* xsl = &xs[tq * CH * DD];   // own token's tile

        #pragma unroll 2
        for (int d = 0; d < DD; d += 4) {
            const float4 w0 = *reinterpret_cast<const float4*>(&Wl[(size_t)(d + 0) * DD + e0]);
            const float4 w1 = *reinterpret_cast<const float4*>(&Wl[(size_t)(d + 1) * DD + e0]);
            const float4 w2 = *reinterpret_cast<const float4*>(&Wl[(size_t)(d + 2) * DD + e0]);
            const float4 w3 = *reinterpret_cast<const float4*>(&Wl[(size_t)(d + 3) * DD + e0]);
            #pragma unroll
            for (int i = 0; i < CH; ++i) {
                const float4 xv = *reinterpret_cast<const float4*>(&xsl[i * DD + d]);
                // d-ascending fmaf chain per (t,e): identical to r1/4/5/6/13/14
                acc[i][0] = fmaf(xv.x, w0.x, acc[i][0]);
                acc[i][1] = fmaf(xv.x, w0.y, acc[i][1]);
                acc[i][2] = fmaf(xv.x, w0.z, acc[i][2]);
                acc[i][3] = fmaf(xv.x, w0.w, acc[i][3]);
                acc[i][0] = fmaf(xv.y, w1.x, acc[i][0]);
                acc[i][1] = fmaf(xv.y, w1.y, acc[i][1]);
                acc[i][2] = fmaf(xv.y, w1.z, acc[i][2]);
                acc[i][3] = fmaf(xv.y, w1.w, acc[i][3]);
                acc[i][0] = fmaf(xv.z, w2.x, acc[i][0]);
                acc[i][1] = fmaf(xv.z, w2.y, acc[i][1]);
                acc[i][2] = fmaf(xv.z, w2.z, acc[i][2]);
                acc[i][3] = fmaf(xv.z, w2.w, acc[i][3]);
                acc[i][0] = fmaf(xv.w, w3.x, acc[i][0]);
                acc[i][1] = fmaf(xv.w, w3.y, acc[i][1]);
                acc[i][2] = fmaf(xv.w, w3.z, acc[i][2]);
                acc[i][3] = fmaf(xv.w, w3.w, acc[i][3]);
            }
        }
        // (no barrier needed here: LIF/g-write only READ xs, same as compute)

        // LIF (identical arithmetic) + g = s?0:x -> bf16 workspace
        #pragma unroll
        for (int i = 0; i < CH; ++i) {
            const int t = tg * CH + i;
            const float4 xv = *reinterpret_cast<const float4*>(&xsl[i * DD + e0]);
            float g[4];
            const float xr[4] = {xv.x, xv.y, xv.z, xv.w};
            #pragma unroll
            for (int e = 0; e < 4; ++e) {
                m[e] = m[e] + (acc[i][e] - m[e]) * 0.5f;
                const float s = (m[e] - 1.0f > 0.0f) ? 1.0f : 0.0f;
                g[e] = (s > 0.0f) ? 0.0f : xr[e];
                m[e] *= (1.0f - s);
            }
            uint2 p;
            p.x = (unsigned)f2bf(g[0]) | ((unsigned)f2bf(g[1]) << 16);
            p.y = (unsigned)f2bf(g[2]) | ((unsigned)f2bf(g[3]) << 16);
            *reinterpret_cast<uint2*>(&gws[((size_t)tok * TT + t) * DD + e0]) = p;
        }
        __syncthreads();   // all xs reads done before next chunk staging
    }
}

// ========== Tier-1 Phase B: pure bf16 GEMM, 2 tokens per wave ==============
// 1024 blocks x 512 thr, 8 waves = (t-half, col-quarter), tokens {2b, 2b+1}.
__global__ __launch_bounds__(512, 2) void lif_phaseB4(
    const unsigned short* __restrict__ gws,  // [B*N*T, D] bf16
    const unsigned short* __restrict__ Wt,   // [D,D] bf16 transposed
    const float* __restrict__ br,            // [D]
    float* __restrict__ out)                 // [T,B,N,D]
{
    const int tid = threadIdx.x;          // 0..511
    const int w    = tid >> 6;            // 0..7
    const int lane = tid & 63;
    const int hB   = w & 1;               // t-half
    const int q    = w >> 1;              // col quarter (128 cols)
    const int lcol = lane & 15;
    const int lkg  = lane >> 4;           // 0..3
    const int tA   = hB * 16 + lcol;      // A row (t) this lane supplies
    const size_t st = (size_t)BB * NN * DD;
    const int colb = q * 128;
    const int tok0 = blockIdx.x * 2;

    const unsigned short* arow0 = &gws[((size_t)tok0 * TT + tA) * DD];
    const unsigned short* arow1 = &gws[((size_t)(tok0 + 1) * TT + tA) * DD];

    f32x4 acc0[8], acc1[8];
    #pragma unroll
    for (int nt = 0; nt < 8; ++nt) {
        const float b = br[colb + nt * 16 + lcol];
        acc0[nt] = (f32x4){b, b, b, b};
        acc1[nt] = (f32x4){b, b, b, b};
    }

    #pragma unroll 1
    for (int ks = 0; ks < 16; ++ks) {
        const int kb = ks * 32 + lkg * 8;
        const short8 a0 = *reinterpret_cast<const short8*>(&arow0[kb]);
        const short8 a1 = *reinterpret_cast<const short8*>(&arow1[kb]);
        #pragma unroll
        for (int nt = 0; nt < 8; ++nt) {
            const int col = colb + nt * 16 + lcol;
            const short8 bf = *reinterpret_cast<const short8*>(&Wt[(size_t)col * DD + kb]);
            acc0[nt] = __builtin_amdgcn_mfma_f32_16x16x32_bf16(a0, bf, acc0[nt], 0, 0, 0);
            acc1[nt] = __builtin_amdgcn_mfma_f32_16x16x32_bf16(a1, bf, acc1[nt], 0, 0, 0);
        }
    }

    // epilogue: C/D layout col=lane&15, row=(lane>>4)*4+r (verified r7/r10/r13)
    #pragma unroll
    for (int nt = 0; nt < 8; ++nt) {
        const int col = colb + nt * 16 + lcol;
        #pragma unroll
        for (int r = 0; r < 4; ++r) {
            const int t = hB * 16 + lkg * 4 + r;
            out[(size_t)t * st + (size_t)tok0 * DD + col]       = acc0[nt][r];
            out[(size_t)t * st + (size_t)(tok0 + 1) * DD + col] = acc1[nt][r];
        }
    }
}

// ========== Tier-2 Phase A: GEMM1+LIF -> global bitmask (r11) ==============
__global__ __launch_bounds__(128, 4) void lif_phaseA_m(
    const float* __restrict__ x, const float* __restrict__ tr_mx,
    const float* __restrict__ Wl, const float* __restrict__ bl,
    unsigned* __restrict__ gmsk)
{
    __shared__ __align__(16) float xs[CH * 256];

    const int tid = threadIdx.x;
    const int tok = blockIdx.x;
    const int e0  = tid * 4;
    const size_t base = (size_t)tok * DD;
    const size_t st   = (size_t)BB * NN * DD;

    float acc[CH][4];
    float4 m4 = *reinterpret_cast<const float4*>(&tr_mx[base + e0]);
    float m[4] = {m4.x, m4.y, m4.z, m4.w};
    unsigned mc[4] = {0u, 0u, 0u, 0u};
    const float4 blv = *reinterpret_cast<const float4*>(&bl[e0]);
    const float blr[4] = {blv.x, blv.y, blv.z, blv.w};

    #pragma unroll 1
    for (int tg = 0; tg < 4; ++tg) {
        #pragma unroll
        for (int i = 0; i < CH; ++i)
            #pragma unroll
            for (int e = 0; e < 4; ++e) acc[i][e] = blr[e];

        #pragma unroll 1
        for (int h = 0; h < 2; ++h) {
            #pragma unroll
            for (int r = 0; r < 4; ++r) {
                const int flat = r * 128 + tid;
                const int row  = flat >> 6;
                const int c4   = flat & 63;
                const float4 v = *reinterpret_cast<const float4*>(
                    &x[(size_t)(tg * CH + row) * st + base + h * 256 + c4 * 4]);
                *reinterpret_cast<float4*>(&xs[row * 256 + c4 * 4]) = v;
            }
            __syncthreads();

            #pragma unroll 2
            for (int dd_ = 0; dd_ < 256; dd_ += 4) {
                const int d = h * 256 + dd_;
                const float4 w0 = *reinterpret_cast<const float4*>(&Wl[(size_t)(d + 0) * DD + e0]);
                const float4 w1 = *reinterpret_cast<const float4*>(&Wl[(size_t)(d + 1) * DD + e0]);
                const float4 w2 = *reinterpret_cast<const float4*>(&Wl[(size_t)(d + 2) * DD + e0]);
                const float4 w3 = *reinterpret_cast<const float4*>(&Wl[(size_t)(d + 3) * DD + e0]);
                #pragma unroll
                for (int i = 0; i < CH; ++i) {
                    const float4 xv = *reinterpret_cast<const float4*>(&xs[i * 256 + dd_]);
                    acc[i][0] = fmaf(xv.x, w0.x, acc[i][0]);
                    acc[i][1] = fmaf(xv.x, w0.y, acc[i][1]);
                    acc[i][2] = fmaf(xv.x, w0.z, acc[i][2]);
                    acc[i][3] = fmaf(xv.x, w0.w, acc[i][3]);
                    acc[i][0] = fmaf(xv.y, w1.x, acc[i][0]);
                    acc[i][1] = fmaf(xv.y, w1.y, acc[i][1]);
                    acc[i][2] = fmaf(xv.y, w1.z, acc[i][2]);
                    acc[i][3] = fmaf(xv.y, w1.w, acc[i][3]);
                    acc[i][0] = fmaf(xv.z, w2.x, acc[i][0]);
                    acc[i][1] = fmaf(xv.z, w2.y, acc[i][1]);
                    acc[i][2] = fmaf(xv.z, w2.z, acc[i][2]);
                    acc[i][3] = fmaf(xv.z, w2.w, acc[i][3]);
                    acc[i][0] = fmaf(xv.w, w3.x, acc[i][0]);
                    acc[i][1] = fmaf(xv.w, w3.y, acc[i][1]);
                    acc[i][2] = fmaf(xv.w, w3.z, acc[i][2]);
                    acc[i][3] = fmaf(xv.w, w3.w, acc[i][3]);
                }
            }
            __syncthreads();
        }

        #pragma unroll
        for (int i = 0; i < CH; ++i) {
            const int t = tg * CH + i;
            #pragma unroll
            for (int e = 0; e < 4; ++e) {
                m[e] = m[e] + (acc[i][e] - m[e]) * 0.5f;
                const float s = (m[e] - 1.0f > 0.0f) ? 1.0f : 0.0f;
                mc[e] |= (s > 0.0f) ? (1u << t) : 0u;
                m[e] *= (1.0f - s);
            }
        }
    }

    uint4 mv;
    mv.x = mc[0]; mv.y = mc[1]; mv.z = mc[2]; mv.w = mc[3];
    *reinterpret_cast<uint4*>(&gmsk[base + e0]) = mv;
}

// ========== Tier-2 Phase B: r12's MFMA GEMM2 (mask + x) ====================
template<bool UW>
__global__ __launch_bounds__(256, 2) void lif_phaseB2(
    const float* __restrict__ x, const float* __restrict__ Wr,
    const float* __restrict__ br, const unsigned short* __restrict__ Wt,
    const unsigned* __restrict__ gmsk, float* __restrict__ out)
{
    __shared__ __align__(16) unsigned ms[2 * DD];

    const int tid = threadIdx.x;
    const size_t st = (size_t)BB * NN * DD;
    {
        const uint4 v = *reinterpret_cast<const uint4*>(
            &gmsk[(size_t)blockIdx.x * 2 * DD + tid * 4]);
        *reinterpret_cast<uint4*>(&ms[tid * 4]) = v;
    }
    __syncthreads();

    const int wv   = tid >> 6;
    const int lane = tid & 63;
    const int qB   = wv >> 1;
    const int hB   = wv & 1;
    const int lcol = lane & 15;
    const int lkg  = lane >> 4;
    const int tA   = hB * 16 + lcol;
    const size_t baseB = (size_t)(blockIdx.x * 2 + qB) * DD;
    const unsigned* mq = &ms[qB * DD];
    const float* xrow = &x[(size_t)tA * st + baseB];

    #pragma unroll 1
    for (int pass = 0; pass < 4; ++pass) {
        const int colb = pass * 128;
        f32x4 acc[8];
        #pragma unroll
        for (int nt = 0; nt < 8; ++nt) {
            const float b = br[colb + nt * 16 + lcol];
            acc[nt] = (f32x4){b, b, b, b};
        }
        #pragma unroll 1
        for (int ks = 0; ks < 16; ++ks) {
            const int kb = ks * 32 + lkg * 8;
            const float4 x0 = *reinterpret_cast<const float4*>(&xrow[kb]);
            const float4 x1 = *reinterpret_cast<const float4*>(&xrow[kb + 4]);
            const uint4 m0 = *reinterpret_cast<const uint4*>(&mq[kb]);
            const uint4 m1 = *reinterpret_cast<const uint4*>(&mq[kb + 4]);
            short8 a;
            a[0] = (short)f2bf(((m0.x >> tA) & 1u) ? 0.0f : x0.x);
            a[1] = (short)f2bf(((m0.y >> tA) & 1u) ? 0.0f : x0.y);
            a[2] = (short)f2bf(((m0.z >> tA) & 1u) ? 0.0f : x0.z);
            a[3] = (short)f2bf(((m0.w >> tA) & 1u) ? 0.0f : x0.w);
            a[4] = (short)f2bf(((m1.x >> tA) & 1u) ? 0.0f : x1.x);
            a[5] = (short)f2bf(((m1.y >> tA) & 1u) ? 0.0f : x1.y);
            a[6] = (short)f2bf(((m1.z >> tA) & 1u) ? 0.0f : x1.z);
            a[7] = (short)f2bf(((m1.w >> tA) & 1u) ? 0.0f : x1.w);
            #pragma unroll
            for (int nt = 0; nt < 8; ++nt) {
                const int col = colb + nt * 16 + lcol;
                short8 bf;
                if (UW) {
                    bf = *reinterpret_cast<const short8*>(&Wt[(size_t)col * DD + kb]);
                } else {
                    #pragma unroll
                    for (int j = 0; j < 8; ++j)
                        bf[j] = (short)f2bf(Wr[(size_t)(kb + j) * DD + col]);
                }
                acc[nt] = __builtin_amdgcn_mfma_f32_16x16x32_bf16(a, bf, acc[nt], 0, 0, 0);
            }
        }
        #pragma unroll
        for (int nt = 0; nt < 8; ++nt) {
            const int col = colb + nt * 16 + lcol;
            #pragma unroll
            for (int r = 0; r < 4; ++r) {
                const int t = hB * 16 + lkg * 4 + r;
                out[(size_t)t * st + baseB + col] = acc[nt][r];
            }
        }
    }
}

extern "C" void kernel_launch(void* const* d_in, const int* in_sizes, int n_in,
                              void* d_out, int out_size, void* d_ws, size_t ws_size,
                              hipStream_t stream) {
    const float* x     = (const float*)d_in[0];
    const float* tr_mx = (const float*)d_in[1];
    const float* Wl    = (const float*)d_in[2];
    const float* bl    = (const float*)d_in[3];
    const float* Wr    = (const float*)d_in[4];
    const float* br    = (const float*)d_in[5];
    float* out = (float*)d_out;

    const size_t g_bytes   = (size_t)BB * NN * TT * DD * 2;   // 67.1 MB
    const size_t wt_bytes  = (size_t)DD * DD * 2;             // 512 KB
    const size_t msk_bytes = (size_t)BB * NN * DD * 4;        // 4 MB

    if (ws_size >= g_bytes + wt_bytes) {
        unsigned short* gws = (unsigned short*)d_ws;
        unsigned short* Wt  = (unsigned short*)((char*)d_ws + g_bytes);
        cast_transpose_wr<<<dim3(1024), dim3(256), 0, stream>>>(Wr, Wt);
        lif_phaseA_g4<<<dim3(BB * NN / 4), dim3(512), 0, stream>>>(x, tr_mx, Wl, bl, gws);
        lif_phaseB4<<<dim3(BB * NN / 2), dim3(512), 0, stream>>>(gws, Wt, br, out);
    } else if (ws_size >= msk_bytes + wt_bytes) {
        unsigned* gmsk = (unsigned*)d_ws;
        unsigned short* Wt = (unsigned short*)((char*)d_ws + msk_bytes);
        cast_transpose_wr<<<dim3(1024), dim3(256), 0, stream>>>(Wr, Wt);
        lif_phaseA_m<<<dim3(BB * NN), dim3(128), 0, stream>>>(x, tr_mx, Wl, bl, gmsk);
        lif_phaseB2<true><<<dim3(BB * NN / 2), dim3(256), 0, stream>>>(x, Wr, br, Wt, gmsk, out);
    } else if (ws_size >= msk_bytes) {
        unsigned* gmsk = (unsigned*)d_ws;
        lif_phaseA_m<<<dim3(BB * NN), dim3(128), 0, stream>>>(x, tr_mx, Wl, bl, gmsk);
        lif_phaseB2<false><<<dim3(BB * NN / 2), dim3(256), 0, stream>>>(x, Wr, br, nullptr, gmsk, out);
    }
}